// Round 1
// baseline (239.813 us; speedup 1.0000x reference)
//
#include <hip/hip_runtime.h>

#define SENT   256
#define BATCH  64
#define WLEN   16
#define D_WORDE 300
#define D_CHARE 50
#define OUT_CH 200
#define KSIZE  3
#define NPOS   14          // WLEN - KSIZE + 1
#define D_OUT  500         // D_WORDE + OUT_CH
#define NWORDS (SENT * BATCH)
#define WELEMS (OUT_CH * D_CHARE * KSIZE)   // 30000

// conv_w [o][c][k] (o*150 + c*3 + k)  ->  cwT [(c*3+k)*200 + o]
__global__ void transpose_w_kernel(const float* __restrict__ conv_w,
                                   float* __restrict__ cwT) {
    int j = blockIdx.x * blockDim.x + threadIdx.x;
    if (j < WELEMS) {
        int o = j / (D_CHARE * KSIZE);
        int r = j % (D_CHARE * KSIZE);
        cwT[r * OUT_CH + o] = conv_w[j];
    }
}

// one wave per (s,b) row; 4 rows per 256-thread block
__global__ void __launch_bounds__(256)
word_emb_kernel(const int* __restrict__ words, const float* __restrict__ W_word,
                float* __restrict__ out) {
    int wave = threadIdx.x >> 6;
    int lane = threadIdx.x & 63;
    int m = blockIdx.x * 4 + wave;            // m = s*64 + b (words is [S][B])
    int idx = words[m];
    const float* __restrict__ src = W_word + (long)idx * D_WORDE;
    float* __restrict__ dst = out + (long)m * D_OUT;
    for (int j = lane; j < D_WORDE; j += 64)
        dst[j] = src[j];
}

// one 256-thread block per word; thread tid<200 owns output channel tid
template <bool TRANSPOSED>
__global__ void __launch_bounds__(256)
char_conv_kernel(const int* __restrict__ chars, const float* __restrict__ W_char,
                 const float* __restrict__ wptr, const float* __restrict__ conv_b,
                 float* __restrict__ out) {
    __shared__ __align__(16) float xs[D_CHARE * WLEN];   // xs[c*16 + l]
    __shared__ int ids[WLEN];
    int m = blockIdx.x;                        // m = s*64 + b
    int s = m >> 6;
    int b = m & 63;
    int tid = threadIdx.x;

    if (tid < WLEN) ids[tid] = chars[(b * SENT + s) * WLEN + tid];
    __syncthreads();
    for (int e = tid; e < D_CHARE * WLEN; e += 256) {
        int c = e >> 4, l = e & 15;
        xs[e] = W_char[ids[l] * D_CHARE + c];
    }
    __syncthreads();

    if (tid < OUT_CH) {
        float acc[NPOS];
        #pragma unroll
        for (int p = 0; p < NPOS; p++) acc[p] = 0.f;

        const float4* xs4 = (const float4*)xs;
        for (int c = 0; c < D_CHARE; c++) {
            float4 a0 = xs4[c * 4 + 0];
            float4 a1 = xs4[c * 4 + 1];
            float4 a2 = xs4[c * 4 + 2];
            float4 a3 = xs4[c * 4 + 3];
            float xr[WLEN] = {a0.x, a0.y, a0.z, a0.w,
                              a1.x, a1.y, a1.z, a1.w,
                              a2.x, a2.y, a2.z, a2.w,
                              a3.x, a3.y, a3.z, a3.w};
            #pragma unroll
            for (int k = 0; k < KSIZE; k++) {
                float w = TRANSPOSED ? wptr[(c * KSIZE + k) * OUT_CH + tid]
                                     : wptr[tid * (D_CHARE * KSIZE) + c * KSIZE + k];
                #pragma unroll
                for (int p = 0; p < NPOS; p++)
                    acc[p] = fmaf(w, xr[p + k], acc[p]);
            }
        }
        float mx = acc[0];
        #pragma unroll
        for (int p = 1; p < NPOS; p++) mx = fmaxf(mx, acc[p]);
        out[(long)m * D_OUT + D_WORDE + tid] = mx + conv_b[tid];
    }
}

extern "C" void kernel_launch(void* const* d_in, const int* in_sizes, int n_in,
                              void* d_out, int out_size, void* d_ws, size_t ws_size,
                              hipStream_t stream) {
    const int*   words  = (const int*)d_in[0];
    const int*   chars  = (const int*)d_in[1];
    const float* W_word = (const float*)d_in[2];
    const float* W_char = (const float*)d_in[3];
    const float* conv_w = (const float*)d_in[4];
    const float* conv_b = (const float*)d_in[5];
    float* out = (float*)d_out;

    hipLaunchKernelGGL(word_emb_kernel, dim3(NWORDS / 4), dim3(256), 0, stream,
                       words, W_word, out);

    if (ws_size >= WELEMS * sizeof(float)) {
        float* cwT = (float*)d_ws;
        hipLaunchKernelGGL(transpose_w_kernel, dim3((WELEMS + 255) / 256), dim3(256),
                           0, stream, conv_w, cwT);
        hipLaunchKernelGGL((char_conv_kernel<true>), dim3(NWORDS), dim3(256), 0, stream,
                           chars, W_char, cwT, conv_b, out);
    } else {
        hipLaunchKernelGGL((char_conv_kernel<false>), dim3(NWORDS), dim3(256), 0, stream,
                           chars, W_char, conv_w, conv_b, out);
    }
}

// Round 2
// 59.598 us; speedup vs baseline: 4.0238x; 4.0238x over previous
//
#include <hip/hip_runtime.h>

#define SENT    256
#define BATCH   64
#define WLEN    16
#define D_WORDE 300
#define D_CHARE 50
#define OUT_CH  200
#define KSIZE   3
#define NPOS    14
#define D_OUT   500
#define NWORDS  (SENT * BATCH)

// ---- MFMA GEMM geometry: M=positions(16/word), N=out_ch (13x16=208), K=3*64=192
#define KPAD     192
#define MPAD     208
#define WPB      16            // words per conv block
#define TILE_U16 1160          // 18 rows * 64 cols + 8 pad (2320 B) per word tile
#define CHARP_U16 (128 * 64)   // padded bf16 char table
#define WO_U16    (MPAD * KPAD)
#define WS_NEED   ((size_t)(CHARP_U16 + WO_U16) * 2)

typedef short  short8  __attribute__((ext_vector_type(8)));
typedef ushort ushort8 __attribute__((ext_vector_type(8)));
typedef float  float4v __attribute__((ext_vector_type(4)));

__device__ __forceinline__ ushort f2bf(float f) {
    unsigned u = __float_as_uint(f);
    u = (u + 0x7FFFu + ((u >> 16) & 1u)) >> 16;   // RNE
    return (ushort)u;
}

// ---------- prep: bf16 padded char table + K-major-padded conv weights ----------
// ws[0 .. 8192)            charP[r=128][c=64]  (c>=50 zero)
// ws[8192 .. 8192+39936)   WO[o=208][kg=192], kg = kk*64 + c ; WO[o][kg] = w[o][c][kk]
__global__ void prep_kernel(const float* __restrict__ W_char,
                            const float* __restrict__ conv_w,
                            ushort* __restrict__ ws) {
    int j = blockIdx.x * 256 + threadIdx.x;
    if (j < CHARP_U16) {
        int r = j >> 6, c = j & 63;
        ws[j] = (c < D_CHARE) ? f2bf(W_char[r * D_CHARE + c]) : (ushort)0;
    }
    int j2 = j - CHARP_U16;
    if (j2 >= 0 && j2 < WO_U16) {
        int o = j2 / KPAD, kg = j2 - o * KPAD;
        int kk = kg >> 6, c = kg & 63;
        float v = (o < OUT_CH && c < D_CHARE)
                    ? conv_w[o * (D_CHARE * KSIZE) + c * KSIZE + kk] : 0.f;
        ws[CHARP_U16 + j2] = f2bf(v);
    }
}

// ---------- word embedding gather (exact f32) ----------
__global__ void __launch_bounds__(256)
word_emb_kernel(const int* __restrict__ words, const float* __restrict__ W_word,
                float* __restrict__ out) {
    int wave = threadIdx.x >> 6;
    int lane = threadIdx.x & 63;
    int m = blockIdx.x * 4 + wave;
    int idx = words[m];
    const float* __restrict__ src = W_word + (size_t)idx * D_WORDE;
    float* __restrict__ dst = out + (size_t)m * D_OUT;
    for (int j = lane; j < D_WORDE; j += 64) dst[j] = src[j];
}

__device__ __forceinline__ float redmax14(float4v d, int lg) {
    float m01 = fmaxf(d[0], d[1]);
    float m23 = fmaxf(d[2], d[3]);
    float m = (lg == 3) ? m01 : fmaxf(m01, m23);   // rows 14,15 invalid
    m = fmaxf(m, __shfl_xor(m, 16, 64));
    m = fmaxf(m, __shfl_xor(m, 32, 64));
    return m;
}

// ---------- conv via MFMA ----------
// 8 waves = 2 groups x 4 waves; group g owns words 8g..8g+7 of the block's 16.
// Wave w of a group owns N-tiles {w, w+4, w+8} (+ tile 12 for one wave per group).
__global__ void __launch_bounds__(512, 2)
conv_mfma_kernel(const int* __restrict__ chars,
                 const ushort* __restrict__ ws,
                 const float* __restrict__ conv_b,
                 float* __restrict__ out) {
    __shared__ __align__(16) ushort smem[WPB * TILE_U16];
    const ushort* __restrict__ charP = ws;
    const ushort* __restrict__ WO    = ws + CHARP_U16;

    const int tid  = threadIdx.x;
    const int lane = tid & 63;
    const int wave = tid >> 6;
    const int g    = wave >> 2;
    const int w    = wave & 3;
    const int l15  = lane & 15;
    const int lg   = lane >> 4;
    const int block0 = blockIdx.x * WPB;

    // ---- hoist weight fragments into registers (once per block)
    const bool has4 = (g == 0) ? (w == 0) : (w == 3);
    const int t0 = w, t1 = w + 4, t2 = w + 8;
    short8 B0[6], B1[6], B2[6], B3[6];
    #pragma unroll
    for (int s = 0; s < 6; s++) {
        B0[s] = *(const short8*)&WO[(t0 * 16 + l15) * KPAD + s * 32 + lg * 8];
        B1[s] = *(const short8*)&WO[(t1 * 16 + l15) * KPAD + s * 32 + lg * 8];
        B2[s] = *(const short8*)&WO[(t2 * 16 + l15) * KPAD + s * 32 + lg * 8];
    }
    if (has4) {
        #pragma unroll
        for (int s = 0; s < 6; s++)
            B3[s] = *(const short8*)&WO[(192 + l15) * KPAD + s * 32 + lg * 8];
    }
    const float bv0 = conv_b[t0 * 16 + l15];
    const float bv1 = conv_b[t1 * 16 + l15];
    const float bv2 = conv_b[t2 * 16 + l15];
    const float bv3 = (has4 && (192 + l15) < OUT_CH) ? conv_b[192 + l15] : 0.f;

    // ---- stage 16 words' char-emb tiles (18 rows x 64 bf16, XOR-swizzled 16B blocks)
    for (int task = tid; task < WPB * 144; task += 512) {
        int word = task / 144;
        int rem  = task - word * 144;
        int l = rem >> 3, blk = rem & 7;
        ushort8 v = {};
        if (l < WLEN) {
            int m  = block0 + word;
            int id = chars[(m & 63) * (SENT * WLEN) + (m >> 6) * WLEN + l];
            v = *(const ushort8*)&charP[id * 64 + blk * 8];
        }
        *(ushort8*)&smem[word * TILE_U16 + l * 64 + ((blk ^ (l & 7)) << 3)] = v;
    }
    __syncthreads();

    // ---- main loop: one word per round per wave-group
    #pragma unroll 1
    for (int r = 0; r < 8; r++) {
        const int widx = g * 8 + r;
        const int m    = block0 + widx;
        const int base = widx * TILE_U16;

        // A fragments: a[s][j] = emb[p + (s>>1)][(s&1)*32 + lg*8 + j], p = l15
        short8 a[6];
        #pragma unroll
        for (int s = 0; s < 6; s++) {
            int l  = l15 + (s >> 1);
            int bb = (((s & 1) * 4 + lg) ^ (l & 7));
            a[s] = *(const short8*)&smem[base + l * 64 + (bb << 3)];
        }

        float4v acc0 = {0,0,0,0}, acc1 = {0,0,0,0}, acc2 = {0,0,0,0}, acc3 = {0,0,0,0};
        #pragma unroll
        for (int s = 0; s < 6; s++) {
            acc0 = __builtin_amdgcn_mfma_f32_16x16x32_bf16(a[s], B0[s], acc0, 0, 0, 0);
            acc1 = __builtin_amdgcn_mfma_f32_16x16x32_bf16(a[s], B1[s], acc1, 0, 0, 0);
            acc2 = __builtin_amdgcn_mfma_f32_16x16x32_bf16(a[s], B2[s], acc2, 0, 0, 0);
            if (has4)
                acc3 = __builtin_amdgcn_mfma_f32_16x16x32_bf16(a[s], B3[s], acc3, 0, 0, 0);
        }

        float* obase = out + (size_t)m * D_OUT + D_WORDE;
        float m0 = redmax14(acc0, lg);
        float m1 = redmax14(acc1, lg);
        float m2 = redmax14(acc2, lg);
        if (lane < 16) {
            obase[t0 * 16 + lane] = m0 + bv0;
            obase[t1 * 16 + lane] = m1 + bv1;
            obase[t2 * 16 + lane] = m2 + bv2;
        }
        if (has4) {
            float m3 = redmax14(acc3, lg);
            if (lane < 8) obase[192 + lane] = m3 + bv3;
        }
    }
}

// ---------- fallback (tiny ws): round-1 f32 kernel, proven correct ----------
__global__ void __launch_bounds__(256)
char_conv_f32_kernel(const int* __restrict__ chars, const float* __restrict__ W_char,
                     const float* __restrict__ conv_w, const float* __restrict__ conv_b,
                     float* __restrict__ out) {
    __shared__ __align__(16) float xs[D_CHARE * WLEN];
    __shared__ int ids[WLEN];
    int m = blockIdx.x, s = m >> 6, b = m & 63, tid = threadIdx.x;
    if (tid < WLEN) ids[tid] = chars[(b * SENT + s) * WLEN + tid];
    __syncthreads();
    for (int e = tid; e < D_CHARE * WLEN; e += 256) {
        int c = e >> 4, l = e & 15;
        xs[e] = W_char[ids[l] * D_CHARE + c];
    }
    __syncthreads();
    if (tid < OUT_CH) {
        float acc[NPOS];
        #pragma unroll
        for (int p = 0; p < NPOS; p++) acc[p] = 0.f;
        const float4* xs4 = (const float4*)xs;
        for (int c = 0; c < D_CHARE; c++) {
            float4 a0 = xs4[c*4+0], a1 = xs4[c*4+1], a2 = xs4[c*4+2], a3 = xs4[c*4+3];
            float xr[WLEN] = {a0.x,a0.y,a0.z,a0.w, a1.x,a1.y,a1.z,a1.w,
                              a2.x,a2.y,a2.z,a2.w, a3.x,a3.y,a3.z,a3.w};
            #pragma unroll
            for (int k = 0; k < KSIZE; k++) {
                float wv = conv_w[tid * (D_CHARE * KSIZE) + c * KSIZE + k];
                #pragma unroll
                for (int p = 0; p < NPOS; p++) acc[p] = fmaf(wv, xr[p + k], acc[p]);
            }
        }
        float mx = acc[0];
        #pragma unroll
        for (int p = 1; p < NPOS; p++) mx = fmaxf(mx, acc[p]);
        out[(size_t)m * D_OUT + D_WORDE + tid] = mx + conv_b[tid];
    }
}

extern "C" void kernel_launch(void* const* d_in, const int* in_sizes, int n_in,
                              void* d_out, int out_size, void* d_ws, size_t ws_size,
                              hipStream_t stream) {
    const int*   words  = (const int*)d_in[0];
    const int*   chars  = (const int*)d_in[1];
    const float* W_word = (const float*)d_in[2];
    const float* W_char = (const float*)d_in[3];
    const float* conv_w = (const float*)d_in[4];
    const float* conv_b = (const float*)d_in[5];
    float* out = (float*)d_out;

    hipLaunchKernelGGL(word_emb_kernel, dim3(NWORDS / 4), dim3(256), 0, stream,
                       words, W_word, out);

    if (ws_size >= WS_NEED) {
        ushort* ws = (ushort*)d_ws;
        hipLaunchKernelGGL(prep_kernel,
                           dim3((CHARP_U16 + WO_U16 + 255) / 256), dim3(256), 0, stream,
                           W_char, conv_w, ws);
        hipLaunchKernelGGL(conv_mfma_kernel, dim3(NWORDS / WPB), dim3(512), 0, stream,
                           chars, ws, conv_b, out);
    } else {
        hipLaunchKernelGGL(char_conv_f32_kernel, dim3(NWORDS), dim3(256), 0, stream,
                           chars, W_char, conv_w, conv_b, out);
    }
}